// Round 2
// baseline (119.640 us; speedup 1.0000x reference)
//
#include <hip/hip_runtime.h>

// Problem constants (from reference)
#define NB 4
#define NN 20000
#define NE 320000
#define HH 128
#define CHUNKS 256   // node-chunks per batch for the weighted-sum kernel

// --- Kernel 1: in-degree histogram (float counts; self-loop added later as +1)
__global__ void deg_kernel(const int* __restrict__ dst, float* __restrict__ deg) {
    int i = blockIdx.x * blockDim.x + threadIdx.x;
    if (i < NE) atomicAdd(&deg[dst[i]], 1.0f);
}

// --- Kernel 2: s[src] += dinv[dst], dinv = rsqrt(deg+1)
__global__ void s_kernel(const int* __restrict__ src, const int* __restrict__ dst,
                         const float* __restrict__ deg, float* __restrict__ s) {
    int i = blockIdx.x * blockDim.x + threadIdx.x;
    if (i < NE) {
        float dinv_dst = rsqrtf(deg[dst[i]] + 1.0f);
        atomicAdd(&s[src[i]], dinv_dst);
    }
}

// --- Kernel 3: v[b,k] = sum_n w[n] * combined[b,n,k]
//     combined[b,n,k] = feat_a[b,n,k] (k<64) else feat_b[b,n,k-64]
//     w[n] = dinv[n]*(dinv[n] + s[n])
// Block = 256 threads = 8 node-subgroups x 32 quad-lanes (each quad-lane owns 4 features).
__global__ void wsum_kernel(const float* __restrict__ fa, const float* __restrict__ fb,
                            const float* __restrict__ deg, const float* __restrict__ s,
                            float* __restrict__ v) {
    __shared__ float4 smem[256];
    const int b = blockIdx.y;
    const int per = (NN + gridDim.x - 1) / gridDim.x;
    const int n0 = blockIdx.x * per;
    const int n1 = min(NN, n0 + per);
    const int t = threadIdx.x;
    const int g = t >> 5;        // node subgroup 0..7
    const int q = t & 31;        // quad lane: 0..15 -> feat_a, 16..31 -> feat_b
    const float* base = (q < 16)
        ? (fa + (size_t)b * NN * 64 + (size_t)q * 4)
        : (fb + (size_t)b * NN * 64 + (size_t)(q - 16) * 4);

    float4 acc = make_float4(0.f, 0.f, 0.f, 0.f);
    for (int n = n0 + g; n < n1; n += 8) {
        float dinv = rsqrtf(deg[n] + 1.0f);
        float w = dinv * (dinv + s[n]);
        float4 x = *reinterpret_cast<const float4*>(base + (size_t)n * 64);
        acc.x += w * x.x; acc.y += w * x.y; acc.z += w * x.z; acc.w += w * x.w;
    }
    smem[t] = acc;
    __syncthreads();
    if (t < 32) {
        float4 r = smem[t];
        #pragma unroll
        for (int gg = 1; gg < 8; ++gg) {
            float4 o = smem[gg * 32 + t];
            r.x += o.x; r.y += o.y; r.z += o.z; r.w += o.w;
        }
        const int k = (t < 16) ? t * 4 : 64 + (t - 16) * 4;
        float* vb = v + b * HH + k;
        atomicAdd(vb + 0, r.x);
        atomicAdd(vb + 1, r.y);
        atomicAdd(vb + 2, r.z);
        atomicAdd(vb + 3, r.w);
    }
}

// --- Kernel 4: tiny MLP head, one block of 128 threads, loops over B=4
// pooled = (v/N) @ W_gcn + b_gcn ; hid = relu(pooled @ W1 + b1) ; out = hid @ W2 + b2
__global__ void mlp_kernel(const float* __restrict__ v,
                           const float* __restrict__ Wg, const float* __restrict__ bg,
                           const float* __restrict__ W1, const float* __restrict__ b1,
                           const float* __restrict__ W2, const float* __restrict__ b2,
                           float* __restrict__ out) {
    __shared__ float xs[HH];
    __shared__ float ys[HH];
    __shared__ float red[HH];
    const int k = threadIdx.x;  // 0..127
    for (int b = 0; b < NB; ++b) {
        xs[k] = v[b * HH + k] * (1.0f / NN);
        __syncthreads();
        float acc = bg[k];
        #pragma unroll 4
        for (int j = 0; j < HH; ++j) acc += xs[j] * Wg[j * HH + k];
        ys[k] = acc;  // pooled
        __syncthreads();
        acc = b1[k];
        #pragma unroll 4
        for (int j = 0; j < HH; ++j) acc += ys[j] * W1[j * HH + k];
        acc = fmaxf(acc, 0.0f);   // relu
        red[k] = acc * W2[k];     // W2 is [H,1]
        __syncthreads();
        for (int off = 64; off > 0; off >>= 1) {
            if (k < off) red[k] += red[k + off];
            __syncthreads();
        }
        if (k == 0) out[b] = red[0] + b2[0];
        __syncthreads();
    }
}

extern "C" void kernel_launch(void* const* d_in, const int* in_sizes, int n_in,
                              void* d_out, int out_size, void* d_ws, size_t ws_size,
                              hipStream_t stream) {
    const float* fa = (const float*)d_in[0];   // [B,N,64]
    const float* fb = (const float*)d_in[1];   // [B,N,64]
    const int*   ei = (const int*)d_in[2];     // [2,E]
    const float* Wg = (const float*)d_in[3];   // [H,H]
    const float* bg = (const float*)d_in[4];   // [H]
    const float* W1 = (const float*)d_in[5];   // [H,H]
    const float* b1 = (const float*)d_in[6];   // [H]
    const float* W2 = (const float*)d_in[7];   // [H,1]
    const float* b2 = (const float*)d_in[8];   // [1]
    float* out = (float*)d_out;

    float* deg = (float*)d_ws;   // N floats
    float* s   = deg + NN;       // N floats
    float* v   = s + NN;         // B*H floats

    // zero deg, s, v (we accumulate with atomics)
    hipMemsetAsync(d_ws, 0, (size_t)(2 * NN + NB * HH) * sizeof(float), stream);

    const int eb = (NE + 255) / 256;
    deg_kernel<<<eb, 256, 0, stream>>>(ei + NE, deg);
    s_kernel<<<eb, 256, 0, stream>>>(ei, ei + NE, deg, s);

    dim3 grid(CHUNKS, NB);
    wsum_kernel<<<grid, 256, 0, stream>>>(fa, fb, deg, s, v);

    mlp_kernel<<<1, HH, 0, stream>>>(v, Wg, bg, W1, b1, W2, b2, out);
}

// Round 3
// 92.232 us; speedup vs baseline: 1.2972x; 1.2972x over previous
//
#include <hip/hip_runtime.h>

// Problem constants (from reference)
#define NB 4
#define NN 20000
#define NE 320000
#define HH 128
#define CHUNKS 256   // node-chunks per batch for the weighted-sum kernel

// --- Kernel 1: in-degree histogram (float counts; self-loop added later as +1)
__global__ void deg_kernel(const int* __restrict__ dst, float* __restrict__ deg) {
    int i = blockIdx.x * blockDim.x + threadIdx.x;
    if (i < NE) atomicAdd(&deg[dst[i]], 1.0f);
}

// --- Kernel 2: s[src] += dinv[dst], dinv = rsqrt(deg+1)
__global__ void s_kernel(const int* __restrict__ src, const int* __restrict__ dst,
                         const float* __restrict__ deg, float* __restrict__ s) {
    int i = blockIdx.x * blockDim.x + threadIdx.x;
    if (i < NE) {
        float dinv_dst = rsqrtf(deg[dst[i]] + 1.0f);
        atomicAdd(&s[src[i]], dinv_dst);
    }
}

// --- Kernel 3: v[b,k] = sum_n w[n] * combined[b,n,k]
//     combined[b,n,k] = feat_a[b,n,k] (k<64) else feat_b[b,n,k-64]
//     w[n] = dinv[n]*(dinv[n] + s[n])
// Block = 256 threads = 8 node-subgroups x 32 quad-lanes (each quad-lane owns 4 features).
__global__ void wsum_kernel(const float* __restrict__ fa, const float* __restrict__ fb,
                            const float* __restrict__ deg, const float* __restrict__ s,
                            float* __restrict__ v) {
    __shared__ float4 smem[256];
    const int b = blockIdx.y;
    const int per = (NN + gridDim.x - 1) / gridDim.x;
    const int n0 = blockIdx.x * per;
    const int n1 = min(NN, n0 + per);
    const int t = threadIdx.x;
    const int g = t >> 5;        // node subgroup 0..7
    const int q = t & 31;        // quad lane: 0..15 -> feat_a, 16..31 -> feat_b
    const float* base = (q < 16)
        ? (fa + (size_t)b * NN * 64 + (size_t)q * 4)
        : (fb + (size_t)b * NN * 64 + (size_t)(q - 16) * 4);

    float4 acc = make_float4(0.f, 0.f, 0.f, 0.f);
    for (int n = n0 + g; n < n1; n += 8) {
        float dinv = rsqrtf(deg[n] + 1.0f);
        float w = dinv * (dinv + s[n]);
        float4 x = *reinterpret_cast<const float4*>(base + (size_t)n * 64);
        acc.x += w * x.x; acc.y += w * x.y; acc.z += w * x.z; acc.w += w * x.w;
    }
    smem[t] = acc;
    __syncthreads();
    if (t < 32) {
        float4 r = smem[t];
        #pragma unroll
        for (int gg = 1; gg < 8; ++gg) {
            float4 o = smem[gg * 32 + t];
            r.x += o.x; r.y += o.y; r.z += o.z; r.w += o.w;
        }
        const int k = (t < 16) ? t * 4 : 64 + (t - 16) * 4;
        float* vb = v + b * HH + k;
        atomicAdd(vb + 0, r.x);
        atomicAdd(vb + 1, r.y);
        atomicAdd(vb + 2, r.z);
        atomicAdd(vb + 3, r.w);
    }
}

// --- Kernel 4: tiny MLP head, one block of B*H = 512 threads (8 waves).
// Thread t owns (b = t>>7, k = t&127). All 4 batches' GEMV columns run
// concurrently; unroll-8 keeps 8 independent weight loads in flight per
// thread, and the 4 batch-groups re-hit the same Wg/W1 lines in L1.
// pooled = (v/N) @ W_gcn + b_gcn ; hid = relu(pooled @ W1 + b1) ; out = hid @ W2 + b2
__global__ void __launch_bounds__(NB * HH) mlp_kernel(
        const float* __restrict__ v,
        const float* __restrict__ Wg, const float* __restrict__ bg,
        const float* __restrict__ W1, const float* __restrict__ b1,
        const float* __restrict__ W2, const float* __restrict__ b2,
        float* __restrict__ out) {
    __shared__ float xs[NB][HH];
    __shared__ float ys[NB][HH];
    __shared__ float red[NB][HH];
    const int t = threadIdx.x;
    const int b = t >> 7;     // 0..3
    const int k = t & (HH - 1);  // 0..127

    xs[b][k] = v[b * HH + k] * (1.0f / NN);
    __syncthreads();

    // layer 1: pooled[b][k]
    float acc = bg[k];
    #pragma unroll 8
    for (int j = 0; j < HH; ++j) acc += xs[b][j] * Wg[j * HH + k];
    ys[b][k] = acc;
    __syncthreads();

    // layer 2: hid[b][k] = relu(...), then scale by W2[k] for the H->1 layer
    acc = b1[k];
    #pragma unroll 8
    for (int j = 0; j < HH; ++j) acc += ys[b][j] * W1[j * HH + k];
    acc = fmaxf(acc, 0.0f);
    red[b][k] = acc * W2[k];
    __syncthreads();

    // tree-reduce 128 -> 1 per batch (all 4 batches in parallel)
    #pragma unroll
    for (int off = HH / 2; off > 0; off >>= 1) {
        if (k < off) red[b][k] += red[b][k + off];
        __syncthreads();
    }
    if (k == 0) out[b] = red[b][0] + b2[0];
}

extern "C" void kernel_launch(void* const* d_in, const int* in_sizes, int n_in,
                              void* d_out, int out_size, void* d_ws, size_t ws_size,
                              hipStream_t stream) {
    const float* fa = (const float*)d_in[0];   // [B,N,64]
    const float* fb = (const float*)d_in[1];   // [B,N,64]
    const int*   ei = (const int*)d_in[2];     // [2,E]
    const float* Wg = (const float*)d_in[3];   // [H,H]
    const float* bg = (const float*)d_in[4];   // [H]
    const float* W1 = (const float*)d_in[5];   // [H,H]
    const float* b1 = (const float*)d_in[6];   // [H]
    const float* W2 = (const float*)d_in[7];   // [H,1]
    const float* b2 = (const float*)d_in[8];   // [1]
    float* out = (float*)d_out;

    float* deg = (float*)d_ws;   // N floats
    float* s   = deg + NN;       // N floats
    float* v   = s + NN;         // B*H floats

    // zero deg, s, v (we accumulate with atomics)
    hipMemsetAsync(d_ws, 0, (size_t)(2 * NN + NB * HH) * sizeof(float), stream);

    const int eb = (NE + 255) / 256;
    deg_kernel<<<eb, 256, 0, stream>>>(ei + NE, deg);
    s_kernel<<<eb, 256, 0, stream>>>(ei, ei + NE, deg, s);

    dim3 grid(CHUNKS, NB);
    wsum_kernel<<<grid, 256, 0, stream>>>(fa, fb, deg, s, v);

    mlp_kernel<<<1, NB * HH, 0, stream>>>(v, Wg, bg, W1, b1, W2, b2, out);
}

// Round 4
// 91.604 us; speedup vs baseline: 1.3061x; 1.0069x over previous
//
#include <hip/hip_runtime.h>

// Problem constants (from reference)
#define NB 4
#define NN 20000
#define NE 320000
#define HH 128
#define CHUNKS 256   // node-chunks per batch for the weighted-sum kernel

#define WS_FLOATS (2 * NN + NB * HH)   // deg + s + v

// --- Kernel 0: zero the workspace (deg, s, v). The runtime's
// hipMemsetAsync fill kernel measured ~40us (tiny occupancy); this is ~2us.
__global__ void zero_kernel(float4* __restrict__ p, int n4) {
    int i = blockIdx.x * blockDim.x + threadIdx.x;
    if (i < n4) p[i] = make_float4(0.f, 0.f, 0.f, 0.f);
}

// --- Kernel 1: in-degree histogram (float counts; self-loop added later as +1)
__global__ void deg_kernel(const int* __restrict__ dst, float* __restrict__ deg) {
    int i = blockIdx.x * blockDim.x + threadIdx.x;
    if (i < NE) atomicAdd(&deg[dst[i]], 1.0f);
}

// --- Kernel 2: s[src] += dinv[dst], dinv = rsqrt(deg+1)
__global__ void s_kernel(const int* __restrict__ src, const int* __restrict__ dst,
                         const float* __restrict__ deg, float* __restrict__ s) {
    int i = blockIdx.x * blockDim.x + threadIdx.x;
    if (i < NE) {
        float dinv_dst = rsqrtf(deg[dst[i]] + 1.0f);
        atomicAdd(&s[src[i]], dinv_dst);
    }
}

// --- Kernel 3: v[b,k] = sum_n w[n] * combined[b,n,k]
//     combined[b,n,k] = feat_a[b,n,k] (k<64) else feat_b[b,n,k-64]
//     w[n] = dinv[n]*(dinv[n] + s[n])
// Block = 256 threads = 8 node-subgroups x 32 quad-lanes (each quad-lane owns 4 features).
__global__ void wsum_kernel(const float* __restrict__ fa, const float* __restrict__ fb,
                            const float* __restrict__ deg, const float* __restrict__ s,
                            float* __restrict__ v) {
    __shared__ float4 smem[256];
    const int b = blockIdx.y;
    const int per = (NN + gridDim.x - 1) / gridDim.x;
    const int n0 = blockIdx.x * per;
    const int n1 = min(NN, n0 + per);
    const int t = threadIdx.x;
    const int g = t >> 5;        // node subgroup 0..7
    const int q = t & 31;        // quad lane: 0..15 -> feat_a, 16..31 -> feat_b
    const float* base = (q < 16)
        ? (fa + (size_t)b * NN * 64 + (size_t)q * 4)
        : (fb + (size_t)b * NN * 64 + (size_t)(q - 16) * 4);

    float4 acc = make_float4(0.f, 0.f, 0.f, 0.f);
    for (int n = n0 + g; n < n1; n += 8) {
        float dinv = rsqrtf(deg[n] + 1.0f);
        float w = dinv * (dinv + s[n]);
        float4 x = *reinterpret_cast<const float4*>(base + (size_t)n * 64);
        acc.x += w * x.x; acc.y += w * x.y; acc.z += w * x.z; acc.w += w * x.w;
    }
    smem[t] = acc;
    __syncthreads();
    if (t < 32) {
        float4 r = smem[t];
        #pragma unroll
        for (int gg = 1; gg < 8; ++gg) {
            float4 o = smem[gg * 32 + t];
            r.x += o.x; r.y += o.y; r.z += o.z; r.w += o.w;
        }
        const int k = (t < 16) ? t * 4 : 64 + (t - 16) * 4;
        float* vb = v + b * HH + k;
        atomicAdd(vb + 0, r.x);
        atomicAdd(vb + 1, r.y);
        atomicAdd(vb + 2, r.z);
        atomicAdd(vb + 3, r.w);
    }
}

// --- Kernel 4: tiny MLP head, one block of B*H = 512 threads (8 waves).
// Thread t owns (b = t>>7, k = t&127). All 4 batches' GEMV columns run
// concurrently; unroll-8 keeps 8 independent weight loads in flight per
// thread, and the 4 batch-groups re-hit the same Wg/W1 lines in L1.
// pooled = (v/N) @ W_gcn + b_gcn ; hid = relu(pooled @ W1 + b1) ; out = hid @ W2 + b2
__global__ void __launch_bounds__(NB * HH) mlp_kernel(
        const float* __restrict__ v,
        const float* __restrict__ Wg, const float* __restrict__ bg,
        const float* __restrict__ W1, const float* __restrict__ b1,
        const float* __restrict__ W2, const float* __restrict__ b2,
        float* __restrict__ out) {
    __shared__ float xs[NB][HH];
    __shared__ float ys[NB][HH];
    __shared__ float red[NB][HH];
    const int t = threadIdx.x;
    const int b = t >> 7;     // 0..3
    const int k = t & (HH - 1);  // 0..127

    xs[b][k] = v[b * HH + k] * (1.0f / NN);
    __syncthreads();

    // layer 1: pooled[b][k]
    float acc = bg[k];
    #pragma unroll 8
    for (int j = 0; j < HH; ++j) acc += xs[b][j] * Wg[j * HH + k];
    ys[b][k] = acc;
    __syncthreads();

    // layer 2: hid[b][k] = relu(...), then scale by W2[k] for the H->1 layer
    acc = b1[k];
    #pragma unroll 8
    for (int j = 0; j < HH; ++j) acc += ys[b][j] * W1[j * HH + k];
    acc = fmaxf(acc, 0.0f);
    red[b][k] = acc * W2[k];
    __syncthreads();

    // tree-reduce 128 -> 1 per batch (all 4 batches in parallel)
    #pragma unroll
    for (int off = HH / 2; off > 0; off >>= 1) {
        if (k < off) red[b][k] += red[b][k + off];
        __syncthreads();
    }
    if (k == 0) out[b] = red[b][0] + b2[0];
}

extern "C" void kernel_launch(void* const* d_in, const int* in_sizes, int n_in,
                              void* d_out, int out_size, void* d_ws, size_t ws_size,
                              hipStream_t stream) {
    const float* fa = (const float*)d_in[0];   // [B,N,64]
    const float* fb = (const float*)d_in[1];   // [B,N,64]
    const int*   ei = (const int*)d_in[2];     // [2,E]
    const float* Wg = (const float*)d_in[3];   // [H,H]
    const float* bg = (const float*)d_in[4];   // [H]
    const float* W1 = (const float*)d_in[5];   // [H,H]
    const float* b1 = (const float*)d_in[6];   // [H]
    const float* W2 = (const float*)d_in[7];   // [H,1]
    const float* b2 = (const float*)d_in[8];   // [1]
    float* out = (float*)d_out;

    float* deg = (float*)d_ws;   // N floats
    float* s   = deg + NN;       // N floats
    float* v   = s + NN;         // B*H floats

    // zero deg, s, v with our own kernel (runtime fill kernel measured ~40us)
    const int n4 = (WS_FLOATS + 3) / 4;  // float4 count (WS_FLOATS = 40512, divisible by 4)
    zero_kernel<<<(n4 + 255) / 256, 256, 0, stream>>>((float4*)d_ws, n4);

    const int eb = (NE + 255) / 256;
    deg_kernel<<<eb, 256, 0, stream>>>(ei + NE, deg);
    s_kernel<<<eb, 256, 0, stream>>>(ei, ei + NE, deg, s);

    dim3 grid(CHUNKS, NB);
    wsum_kernel<<<grid, 256, 0, stream>>>(fa, fb, deg, s, v);

    mlp_kernel<<<1, NB * HH, 0, stream>>>(v, Wg, bg, W1, b1, W2, b2, out);
}